// Round 1
// baseline (1718.343 us; speedup 1.0000x reference)
//
#include <hip/hip_runtime.h>

#define PRE   2048
#define POST  2048
#define BATCH 64
#define HIST  50

// output layout (floats), in reference return order
#define OFF_SYN      0           // [64][2048]
#define OFF_PRE_ACT  131072      // [2048]
#define OFF_POST_ACT 133120      // [2048]
#define OFF_HIST     135168      // [2048][2048][50]
#define OFF_LIFE     209850368   // [2048][2048]
#define OFF_AVG      214044672   // [2048][2048]

// ---------------------------------------------------------------------------
// Kernel 1: batch means + EMA activity traces; also zero the synaptic_current
// region (d_out is poisoned 0xAA before every timed call; k_matmul atomically
// accumulates into it).
// grid 16 x 256 = 4096 threads
// ---------------------------------------------------------------------------
__global__ __launch_bounds__(256) void k_means(
    const float* __restrict__ pre, const float* __restrict__ post,
    const float* __restrict__ pre_act, const float* __restrict__ post_act,
    float* __restrict__ out, float* __restrict__ ws_means) {
  const int t = blockIdx.x * 256 + threadIdx.x;  // 0..4095

  // zero syn region: 131072 floats = 32768 float4 / 4096 threads = 8 each
  float4* outz = reinterpret_cast<float4*>(out + OFF_SYN);
  const float4 z = make_float4(0.f, 0.f, 0.f, 0.f);
#pragma unroll
  for (int i = 0; i < 8; ++i) outz[t + i * 4096] = z;

  if (t < PRE) {
    float s = 0.f;
#pragma unroll 8
    for (int b = 0; b < BATCH; ++b) s += pre[b * PRE + t];
    const float m = s * (1.0f / BATCH);
    ws_means[t] = m;
    out[OFF_PRE_ACT + t] = 0.99f * pre_act[t] + 0.01f * m;
  } else {
    const int c = t - PRE;
    float s = 0.f;
#pragma unroll 8
    for (int b = 0; b < BATCH; ++b) s += post[b * POST + c];
    const float m = s * (1.0f / BATCH);
    ws_means[PRE + c] = m;
    out[OFF_POST_ACT + c] = 0.99f * post_act[c] + 0.01f * m;
  }
}

// ---------------------------------------------------------------------------
// Kernel 2: synaptic_current = pre_spikes @ (W * M), fp32 (no fp32 MFMA on
// CDNA4 -> vector FMA). Split-K=32 so grid = 8 j-tiles * 32 k-splits = 256
// blocks (1/CU). Per block: j-tile=256, k-range=64, full batch=64.
// ew tile staged in LDS (64 KB); pre read direct (16 KB tile, L1-resident,
// uniform across the 32 j-lanes of each half-wave). 8x8 register tile.
// ---------------------------------------------------------------------------
__global__ __launch_bounds__(256) void k_matmul(
    const float* __restrict__ pre, const float* __restrict__ W,
    const float* __restrict__ M, float* __restrict__ out) {
  __shared__ float ew[64 * 256];  // 64 KB

  const int jt = blockIdx.x & 7;   // 8 j-tiles of 256
  const int ks = blockIdx.x >> 3;  // 32 k-splits of 64
  const int j0 = jt * 256;
  const int k0 = ks * 64;
  const int t = threadIdx.x;

  // stage ew = W*M for [k0:k0+64][j0:j0+256], float4-coalesced
#pragma unroll
  for (int it = 0; it < 16; ++it) {
    const int lin = (t + it * 256) * 4;  // 0..65532
    const int kk = lin >> 8;
    const int jj = lin & 255;
    const float4 w4 = *reinterpret_cast<const float4*>(&W[(k0 + kk) * POST + j0 + jj]);
    const float4 m4 = *reinterpret_cast<const float4*>(&M[(k0 + kk) * POST + j0 + jj]);
    float4 e;
    e.x = w4.x * m4.x; e.y = w4.y * m4.y; e.z = w4.z * m4.z; e.w = w4.w * m4.w;
    *reinterpret_cast<float4*>(&ew[kk * 256 + jj]) = e;
  }
  __syncthreads();

  const int tj = t & 31;   // 32 j-threads * 8 cols = 256
  const int tb = t >> 5;   // 8 b-groups * 8 rows = 64
  const int jb = tj * 8;
  const int bb0 = tb * 8;

  float acc[8][8];
#pragma unroll
  for (int r = 0; r < 8; ++r)
#pragma unroll
    for (int c = 0; c < 8; ++c) acc[r][c] = 0.f;

  const float4* ew4 = reinterpret_cast<const float4*>(ew);

  for (int kk4 = 0; kk4 < 16; ++kk4) {
    float4 pr[8];
#pragma unroll
    for (int r = 0; r < 8; ++r)
      pr[r] = *reinterpret_cast<const float4*>(&pre[(bb0 + r) * PRE + k0 + kk4 * 4]);
#pragma unroll
    for (int e = 0; e < 4; ++e) {
      const int kk = kk4 * 4 + e;
      const float4 e0 = ew4[kk * 64 + tj * 2];
      const float4 e1 = ew4[kk * 64 + tj * 2 + 1];
#pragma unroll
      for (int r = 0; r < 8; ++r) {
        const float pv = (e == 0) ? pr[r].x : (e == 1) ? pr[r].y : (e == 2) ? pr[r].z : pr[r].w;
        acc[r][0] += pv * e0.x; acc[r][1] += pv * e0.y;
        acc[r][2] += pv * e0.z; acc[r][3] += pv * e0.w;
        acc[r][4] += pv * e1.x; acc[r][5] += pv * e1.y;
        acc[r][6] += pv * e1.z; acc[r][7] += pv * e1.w;
      }
    }
  }

#pragma unroll
  for (int r = 0; r < 8; ++r)
#pragma unroll
    for (int c = 0; c < 8; ++c)
      unsafeAtomicAdd(&out[OFF_SYN + (bb0 + r) * POST + j0 + jb + c], acc[r][c]);
}

// ---------------------------------------------------------------------------
// Kernel 3 (dominant): history copy + slice replace + fused avg + lifetimes.
// Each block owns 256 pairs = 12800 contiguous floats of history.
// Phase A: float4-coalesced read->write with h==idx element replaced,
//          mirrored into LDS with stride-51 padding.
// Phase B: thread t sums pair t's 50 values (stride-51: conflict-free-ish),
//          writes avg_correlation; fuses lifetimes update (all coalesced).
// ---------------------------------------------------------------------------
__global__ __launch_bounds__(256) void k_history(
    const float* __restrict__ hist_in, const float* __restrict__ mask,
    const float* __restrict__ life_in, const float* __restrict__ ws_means,
    const int* __restrict__ corr_idx, float* __restrict__ out) {
  __shared__ float lds[256 * 51];  // 52224 B -> 3 blocks/CU

  const int t = threadIdx.x;
  const int pair0 = blockIdx.x * 256;          // first pair of this tile
  const int i_row = pair0 >> 11;               // constant per block (256 | 2048)
  const int jbase = pair0 & 2047;

  int idx = corr_idx[0] % HIST;
  if (idx < 0) idx += HIST;

  const float mp_i = ws_means[i_row];
  const float* __restrict__ hsrc = hist_in + (size_t)pair0 * HIST;
  float* __restrict__ hdst = out + OFF_HIST + (size_t)pair0 * HIST;
  const float* __restrict__ mpost = ws_means + PRE + jbase;

  // Phase A: 12800 floats = 3200 float4
  for (int v = t; v < 3200; v += 256) {
    const int f = v * 4;
    float4 x = *reinterpret_cast<const float4*>(&hsrc[f]);
    float vals[4] = {x.x, x.y, x.z, x.w};
#pragma unroll
    for (int e = 0; e < 4; ++e) {
      const int ff = f + e;
      const int p = ff / 50;        // magic-mul (const divisor)
      const int h = ff - p * 50;
      float val = vals[e];
      if (h == idx) val = mp_i * mpost[p];
      lds[p * 51 + h] = val;
      vals[e] = val;
    }
    x.x = vals[0]; x.y = vals[1]; x.z = vals[2]; x.w = vals[3];
    *reinterpret_cast<float4*>(&hdst[f]) = x;
  }
  __syncthreads();

  // Phase B: per-pair mean + lifetimes
  float s = 0.f;
#pragma unroll
  for (int h = 0; h < HIST; ++h) s += lds[t * 51 + h];
  const size_t pg = (size_t)pair0 + t;
  out[OFF_AVG + pg] = s * (1.0f / HIST);
  out[OFF_LIFE + pg] = life_in[pg] + mask[pg];
}

// ---------------------------------------------------------------------------
extern "C" void kernel_launch(void* const* d_in, const int* in_sizes, int n_in,
                              void* d_out, int out_size, void* d_ws, size_t ws_size,
                              hipStream_t stream) {
  const float* pre   = (const float*)d_in[0];
  const float* post  = (const float*)d_in[1];
  // d_in[2] = current_time (unused: plasticity branch statically skipped)
  const float* W     = (const float*)d_in[3];
  const float* Mask  = (const float*)d_in[4];
  const float* preA  = (const float*)d_in[5];
  const float* postA = (const float*)d_in[6];
  const float* hist  = (const float*)d_in[7];
  const float* life  = (const float*)d_in[8];
  const int*   cidx  = (const int*)d_in[9];
  float* out = (float*)d_out;
  float* means = (float*)d_ws;  // 4096 floats scratch

  k_means<<<16, 256, 0, stream>>>(pre, post, preA, postA, out, means);
  k_matmul<<<256, 256, 0, stream>>>(pre, W, Mask, out);
  k_history<<<16384, 256, 0, stream>>>(hist, Mask, life, means, cidx, out);
}